// Round 7
// baseline (332.391 us; speedup 1.0000x reference)
//
#include <hip/hip_runtime.h>
#include <hip/hip_bf16.h>

#define NB 128
#define NT 1024
#define NOBS 512
#define NH 64
#define NP 128
#define NM (NB*NT)      // 131072 rows
#define NN2 256
#define NCH 16
#define CHL 64

typedef short bf16x8 __attribute__((ext_vector_type(8)));
typedef float f32x4 __attribute__((ext_vector_type(4)));

// ---- ws layout (bytes) ----
#define FLAG_OFF  ((size_t)83886080)       // 128*16 int flags
#define CONST_OFF ((size_t)91226112)
#define CONST_STRIDE ((size_t)131072)
#define WTB_OFF   ((size_t)92274688)
// const block: [0,1024) lambar f32x2; [1024,33792) Bglob bf16 [256][64];
// [33792,66560) Cglob bf16 [64][256]; [66560,74752) gwT bf16 [64][64]

__device__ __forceinline__ unsigned short f2b(float f) {
  unsigned int u = __float_as_uint(f);
  u = u + 0x7fffu + ((u >> 16) & 1u);
  return (unsigned short)(u >> 16);
}
__device__ __forceinline__ float b2f(unsigned short s) {
  return __uint_as_float(((unsigned int)s) << 16);
}
__device__ __forceinline__ unsigned int pk2(float lo, float hi) {
  // packed bf16 pair (RNE), lo -> bits[15:0]
  return (unsigned int)f2b(lo) | ((unsigned int)f2b(hi) << 16);
}

// ---------------- setup: per-layer constant tables + dense W^T bf16 + flag zero ----------------
__global__ __launch_bounds__(256) void k_setup(const float* Lre, const float* Lim,
    const float* Bp, const float* Cp, const float* lstep, const float* gw,
    const float* dw, unsigned char* wsb) {
  int l = blockIdx.y;
  int idx = blockIdx.x * 256 + threadIdx.x;   // [0,16384)
  unsigned char* cb = wsb + CONST_OFF + (size_t)l * CONST_STRIDE;
  float2* lambar = (float2*)cb;
  unsigned short* Bglob = (unsigned short*)(cb + 1024);
  unsigned short* Cglob = (unsigned short*)(cb + 33792);
  unsigned short* gwT   = (unsigned short*)(cb + 66560);
  if (l == 0 && idx < NB * NCH) ((int*)(wsb + FLAG_OFF))[idx] = 0;
  {
    int n = idx >> 6, h = idx & 63, p = n >> 1, c = n & 1;
    float step = expf(lstep[l * NP + p]);
    float re = Lre[l * NP + p], im = Lim[l * NP + p];
    float er = expf(re * step), ang = im * step;
    float lbr = er * cosf(ang), lbi = er * sinf(ang);
    if (h == 0 && c == 0) lambar[p] = make_float2(lbr, lbi);
    float den = re * re + im * im;
    float nr = lbr - 1.f, ni = lbi;
    float dr = (nr * re + ni * im) / den;
    float di = (ni * re - nr * im) / den;
    size_t bb = ((size_t)(l * NP + p) * NH + h) * 2;
    float b0 = Bp[bb + 0], b1 = Bp[bb + 1];
    float vr = dr * b0 - di * b1;
    float vi = dr * b1 + di * b0;
    Bglob[n * 64 + h] = f2b(c ? vi : vr);
  }
  {
    int h = idx >> 8, n = idx & 255, p = n >> 1;
    size_t base = ((size_t)(l * NH + h) * NP + p) * 2;
    float val = (n & 1) ? (-2.f * Cp[base + 1]) : (2.f * Cp[base + 0]);
    Cglob[h * 256 + n] = f2b(val);
  }
  if (idx < 4096) {
    int n = idx >> 6, k = idx & 63;
    gwT[n * 64 + k] = f2b(gw[(size_t)(l * NH + k) * NH + n]);
  }
  {
    int idx2 = l * 16384 + idx;
    int h = idx2 >> 9, k = idx2 & 511;
    ((unsigned short*)(wsb + WTB_OFF))[h * 512 + k] = f2b(dw[(size_t)k * NH + h]);
  }
}

// ---------------- dense: x = obs @ W + b (pipelined, BK=64) ----------------
__global__ __launch_bounds__(256) void k_dense(const float* __restrict__ obs,
    const unsigned short* __restrict__ wTb, const float* __restrict__ bias,
    float* __restrict__ xout) {
  __shared__ __align__(16) unsigned short As[128][72];
  __shared__ __align__(16) unsigned short Bs[64][72];
  int tid = threadIdx.x, lane = tid & 63, wv = tid >> 6;
  int row0 = blockIdx.x * 128;
  f32x4 acc[2][4] = {};
  float bcol[4];
#pragma unroll
  for (int ct = 0; ct < 4; ++ct) bcol[ct] = bias[ct * 16 + (lane & 15)];
  float4 ra[8];
  uint4 rb[2];
#pragma unroll
  for (int i = 0; i < 8; ++i) {
    int id = tid + i * 256;
    ra[i] = *(const float4*)(obs + (size_t)(row0 + (id >> 4)) * NOBS + (id & 15) * 4);
  }
#pragma unroll
  for (int i = 0; i < 2; ++i) {
    int id = tid + i * 256;
    rb[i] = *(const uint4*)(wTb + (id >> 3) * 512 + (id & 7) * 8);
  }
  for (int kt = 0; kt < 8; ++kt) {
#pragma unroll
    for (int i = 0; i < 8; ++i) {
      int id = tid + i * 256;
      ushort4 o; o.x = f2b(ra[i].x); o.y = f2b(ra[i].y); o.z = f2b(ra[i].z); o.w = f2b(ra[i].w);
      *(ushort4*)&As[id >> 4][(id & 15) * 4] = o;
    }
#pragma unroll
    for (int i = 0; i < 2; ++i) {
      int id = tid + i * 256;
      *(uint4*)&Bs[id >> 3][(id & 7) * 8] = rb[i];
    }
    __syncthreads();
    if (kt < 7) {
      int k0 = (kt + 1) * 64;
#pragma unroll
      for (int i = 0; i < 8; ++i) {
        int id = tid + i * 256;
        ra[i] = *(const float4*)(obs + (size_t)(row0 + (id >> 4)) * NOBS + k0 + (id & 15) * 4);
      }
#pragma unroll
      for (int i = 0; i < 2; ++i) {
        int id = tid + i * 256;
        rb[i] = *(const uint4*)(wTb + (id >> 3) * 512 + k0 + (id & 7) * 8);
      }
    }
#pragma unroll
    for (int kc = 0; kc < 2; ++kc) {
      bf16x8 a0 = *(const bf16x8*)&As[wv * 32 + (lane & 15)][kc * 32 + (lane >> 4) * 8];
      bf16x8 a1 = *(const bf16x8*)&As[wv * 32 + 16 + (lane & 15)][kc * 32 + (lane >> 4) * 8];
#pragma unroll
      for (int ct = 0; ct < 4; ++ct) {
        bf16x8 bb = *(const bf16x8*)&Bs[ct * 16 + (lane & 15)][kc * 32 + (lane >> 4) * 8];
        acc[0][ct] = __builtin_amdgcn_mfma_f32_16x16x32_bf16(a0, bb, acc[0][ct], 0, 0, 0);
        acc[1][ct] = __builtin_amdgcn_mfma_f32_16x16x32_bf16(a1, bb, acc[1][ct], 0, 0, 0);
      }
    }
    __syncthreads();
  }
  float* Os = (float*)&As[0][0];   // [64][68]
#pragma unroll
  for (int pass = 0; pass < 2; ++pass) {
    if ((wv >> 1) == pass) {
#pragma unroll
      for (int rt = 0; rt < 2; ++rt)
#pragma unroll
        for (int ct = 0; ct < 4; ++ct)
#pragma unroll
          for (int e = 0; e < 4; ++e) {
            int rl = (wv & 1) * 32 + rt * 16 + (lane >> 4) * 4 + e;
            int col = ct * 16 + (lane & 15);
            Os[rl * 68 + col] = acc[rt][ct][e] + bcol[ct];
          }
    }
    __syncthreads();
    {
      int r = tid >> 2, seg = tid & 3;
#pragma unroll
      for (int i = 0; i < 4; ++i)
        *(float4*)(xout + (size_t)(row0 + pass * 64 + r) * NH + seg * 16 + i * 4) =
            *(const float4*)&Os[r * 68 + seg * 16 + i * 4];
    }
    __syncthreads();
  }
}

// ---------------- per-layer kernel, producer-consumer pipelined across 2 blocks/b ----------------
// grid (NB, 2): blockIdx.y = layer. Layer-0 block publishes x chunk j via flag[b][j]
// (device-scope release); layer-1 block spins (relaxed+acquire) before consuming.
__global__ __launch_bounds__(512, 1) void k_layer(float* __restrict__ x,
    const int* __restrict__ dones, const unsigned char* __restrict__ cb0,
    const float* __restrict__ hidden, float* __restrict__ hout,
    const float* __restrict__ nsc0, const float* __restrict__ nbi0,
    const float* __restrict__ Dv0, const float* __restrict__ gb0,
    int* __restrict__ flagv) {
  __shared__ __align__(16) unsigned short Bs[256][72];      // 36864
  __shared__ __align__(16) unsigned short Cs[64][264];      // 33792
  __shared__ __align__(16) unsigned short BuS[2][64][264];  // 67584
  __shared__ __align__(16) unsigned short xnS[64][72];      // 9216
  __shared__ __align__(16) unsigned short Ys[64][72];       // 9216
  __shared__ int dS[1024];                                  // 4096
  __shared__ float murs[4][64][2];                          // 2048  => 162816 B
  int tid = threadIdx.x, lane = tid & 63, wv = tid >> 6;
  int b = blockIdx.x;
  int l = blockIdx.y;
  const unsigned char* cb = cb0 + (size_t)l * CONST_STRIDE;
  const float* nsc = nsc0 + l * NH;
  const float* nbi = nbi0 + l * NH;
  const float* Dv  = Dv0 + l * NH;
  const float* gb  = gb0 + l * NH;
  const unsigned short* Bglob = (const unsigned short*)(cb + 1024);
  const unsigned short* Cglob = (const unsigned short*)(cb + 33792);
  const unsigned short* gwT = (const unsigned short*)(cb + 66560);
  int* flg = flagv + b * NCH;

  // stage tables
  {
    int r = tid >> 1, h0 = (tid & 1) * 32;
#pragma unroll
    for (int i = 0; i < 4; ++i)
      *(uint4*)&Bs[r][h0 + i * 8] = *(const uint4*)(Bglob + r * 64 + h0 + i * 8);
  }
  {
    int r = tid >> 3, s0 = (tid & 7) * 32;
#pragma unroll
    for (int i = 0; i < 4; ++i)
      *(uint4*)&Cs[r][s0 + i * 8] = *(const uint4*)(Cglob + r * 256 + s0 + i * 8);
  }
  dS[tid] = dones[b * NT + tid];
  dS[tid + 512] = dones[b * NT + 512 + tid];

  // consumer: wait for chunk 0 before any x read
  if (l == 1) {
    while (__hip_atomic_load(&flg[0], __ATOMIC_RELAXED, __HIP_MEMORY_SCOPE_AGENT) == 0)
      __builtin_amdgcn_s_sleep(8);
    (void)__hip_atomic_load(&flg[0], __ATOMIC_ACQUIRE, __HIP_MEMORY_SCOPE_AGENT);
  }

  // role preloads
  float4 pre0, pre1, pre2, pre3;
  float nscr[16], nbir[16];
  float lamr = 0.f, lami = 0.f, hr = 0.f, hi = 0.f;
  float Dr[4], nscc[4], nbic[4], gbr[4];
  if (tid < 256) {
    int q = tid & 3;
#pragma unroll
    for (int j = 0; j < 16; ++j) { nscr[j] = nsc[q * 16 + j]; nbir[j] = nbi[q * 16 + j]; }
    int r = tid >> 2;
    const float* xr = x + ((size_t)b * NT + r) * NH + q * 16;
    pre0 = *(const float4*)(xr);     pre1 = *(const float4*)(xr + 4);
    pre2 = *(const float4*)(xr + 8); pre3 = *(const float4*)(xr + 12);
  } else {
#pragma unroll
    for (int ct = 0; ct < 4; ++ct) {
      int col = ct * 16 + (lane & 15);
      Dr[ct] = Dv[col]; nscc[ct] = nsc[col]; nbic[ct] = nbi[col]; gbr[ct] = gb[col];
    }
    if (tid < 384) {
      int p = tid - 256;
      float2 lm = ((const float2*)cb)[p];
      lamr = lm.x; lami = lm.y;
      size_t hoff = (((size_t)l * NB + b) * NP + p) * 2;
      hr = hidden[hoff]; hi = hidden[hoff + 1];
    }
  }
  __syncthreads();

#pragma unroll 1
  for (int i = 0; i < NCH + 2; ++i) {
    // consumer: gate next chunk's prefetch
    if (l == 1 && i < NCH - 1) {
      while (__hip_atomic_load(&flg[i + 1], __ATOMIC_RELAXED, __HIP_MEMORY_SCOPE_AGENT) == 0)
        __builtin_amdgcn_s_sleep(8);
      (void)__hip_atomic_load(&flg[i + 1], __ATOMIC_ACQUIRE, __HIP_MEMORY_SCOPE_AGENT);
    }
    float yreg[4][4], xres[4][4];
    // ---------------- P1a ----------------
    if (tid < 256) {
      if (i < NCH) {
        float vv[16];
        *(float4*)&vv[0] = pre0;  *(float4*)&vv[4] = pre1;
        *(float4*)&vv[8] = pre2;  *(float4*)&vv[12] = pre3;
        int r = tid >> 2, q = tid & 3;
        if (i < NCH - 1) {
          const float* xr = x + ((size_t)b * NT + (i + 1) * CHL + r) * NH + q * 16;
          pre0 = *(const float4*)(xr);     pre1 = *(const float4*)(xr + 4);
          pre2 = *(const float4*)(xr + 8); pre3 = *(const float4*)(xr + 12);
        }
        float s = 0.f, s2 = 0.f;
#pragma unroll
        for (int j = 0; j < 16; ++j) { s += vv[j]; s2 += vv[j] * vv[j]; }
        s += __shfl_xor(s, 1); s2 += __shfl_xor(s2, 1);
        s += __shfl_xor(s, 2); s2 += __shfl_xor(s2, 2);
        float mu = s * 0.015625f;
        float var = s2 * 0.015625f - mu * mu;
        float rs = rsqrtf(var + 1e-6f);
        if (q == 0) { murs[i & 3][r][0] = mu; murs[i & 3][r][1] = rs; }
#pragma unroll
        for (int k = 0; k < 8; ++k) {
          float a0 = (vv[2 * k] - mu) * rs * nscr[2 * k] + nbir[2 * k];
          float a1 = (vv[2 * k + 1] - mu) * rs * nscr[2 * k + 1] + nbir[2 * k + 1];
          *(unsigned int*)&xnS[r][q * 16 + 2 * k] = pk2(a0, a1);
        }
      }
    } else if (i >= 2) {
      int j = i - 2, wv2 = wv - 4;
#pragma unroll
      for (int ct = 0; ct < 4; ++ct)
#pragma unroll
        for (int e = 0; e < 4; ++e) {
          int rl = wv2 * 16 + (lane >> 4) * 4 + e;
          xres[ct][e] = x[((size_t)b * NT + j * CHL + rl) * NH + ct * 16 + (lane & 15)];
        }
      f32x4 acc[4] = {};
      const unsigned short (*Bu)[264] = BuS[j & 1];
#pragma unroll
      for (int kc = 0; kc < 8; ++kc) {
        bf16x8 a = *(const bf16x8*)&Bu[wv2 * 16 + (lane & 15)][kc * 32 + (lane >> 4) * 8];
#pragma unroll
        for (int ct = 0; ct < 4; ++ct) {
          bf16x8 bbf = *(const bf16x8*)&Cs[ct * 16 + (lane & 15)][kc * 32 + (lane >> 4) * 8];
          acc[ct] = __builtin_amdgcn_mfma_f32_16x16x32_bf16(a, bbf, acc[ct], 0, 0, 0);
        }
      }
#pragma unroll
      for (int ct = 0; ct < 4; ++ct)
#pragma unroll
        for (int e = 0; e < 4; ++e) {
          int rl = wv2 * 16 + (lane >> 4) * 4 + e;
          float mu = murs[j & 3][rl][0], rs = murs[j & 3][rl][1];
          float xnv = (xres[ct][e] - mu) * rs * nscc[ct] + nbic[ct];
          float yv = acc[ct][e] + Dr[ct] * xnv;
          float t3 = 0.7978845608f * (yv + 0.044715f * yv * yv * yv);
          float u = __expf(2.f * t3);
          yv = 0.5f * yv * (2.f - 2.f / (u + 1.f));
          yreg[ct][e] = yv;
          Ys[rl][ct * 16 + (lane & 15)] = f2b(yv);
        }
    }
    __syncthreads();
    // ---------------- P1b ----------------
    if (tid >= 256 && i >= 2) {
      int j = i - 2, wv2 = wv - 4;
      f32x4 gacc[4] = {};
#pragma unroll
      for (int kc = 0; kc < 2; ++kc) {
        bf16x8 a = *(const bf16x8*)&Ys[wv2 * 16 + (lane & 15)][kc * 32 + (lane >> 4) * 8];
#pragma unroll
        for (int ct = 0; ct < 4; ++ct) {
          bf16x8 bbf = *(const bf16x8*)(gwT + (ct * 16 + (lane & 15)) * 64 + kc * 32 + (lane >> 4) * 8);
          gacc[ct] = __builtin_amdgcn_mfma_f32_16x16x32_bf16(a, bbf, gacc[ct], 0, 0, 0);
        }
      }
#pragma unroll
      for (int ct = 0; ct < 4; ++ct)
#pragma unroll
        for (int e = 0; e < 4; ++e) {
          int rl = wv2 * 16 + (lane >> 4) * 4 + e;
          float g = gacc[ct][e] + gbr[ct];
          float sg = 1.f / (1.f + __expf(-g));
          x[((size_t)b * NT + j * CHL + rl) * NH + ct * 16 + (lane & 15)] =
              xres[ct][e] + yreg[ct][e] * sg;
        }
    }
    __syncthreads();
    // producer: publish chunk i-2 (x stores drained by the barrier above)
    if (l == 0 && i >= 2 && tid == 511)
      __hip_atomic_store(&flg[i - 2], 1, __ATOMIC_RELEASE, __HIP_MEMORY_SCOPE_AGENT);
    // ---------------- P2 ----------------
    if (tid < 256) {
      if (i < NCH) {
        // swapped operands: acc[ct] holds Bu^T tile -> same-lane (re,im) pairs
        f32x4 acc[16] = {};
#pragma unroll
        for (int kc = 0; kc < 2; ++kc) {
          bf16x8 a = *(const bf16x8*)&xnS[wv * 16 + (lane & 15)][kc * 32 + (lane >> 4) * 8];
#pragma unroll
          for (int ct = 0; ct < 16; ++ct) {
            bf16x8 bbf = *(const bf16x8*)&Bs[ct * 16 + (lane & 15)][kc * 32 + (lane >> 4) * 8];
            acc[ct] = __builtin_amdgcn_mfma_f32_16x16x32_bf16(bbf, a, acc[ct], 0, 0, 0);
          }
        }
        unsigned short (*Bu)[264] = BuS[i & 1];
        int t = wv * 16 + (lane & 15), cb4 = (lane >> 4) * 4;
#pragma unroll
        for (int ct = 0; ct < 16; ++ct) {
          *(unsigned int*)&Bu[t][ct * 16 + cb4]     = pk2(acc[ct][0], acc[ct][1]);
          *(unsigned int*)&Bu[t][ct * 16 + cb4 + 2] = pk2(acc[ct][2], acc[ct][3]);
        }
      }
    } else if (tid < 384 && i >= 1 && i <= NCH) {
      int ch = i - 1, p = tid - 256;
      unsigned short (*Bu)[264] = BuS[ch & 1];
#pragma unroll 4
      for (int t = 0; t < CHL; ++t) {
        unsigned int u = *(const unsigned int*)&Bu[t][2 * p];
        float bur = b2f((unsigned short)(u & 0xffffu));
        float bui = b2f((unsigned short)(u >> 16));
        if (dS[ch * CHL + t]) { hr = bur; hi = bui; }
        else {
          float nr = lamr * hr - lami * hi + bur;
          hi = lamr * hi + lami * hr + bui; hr = nr;
        }
        *(unsigned int*)&Bu[t][2 * p] = pk2(hr, hi);
      }
      if (i == NCH) {
        size_t hoff = (((size_t)l * NB + b) * NP + p) * 2;
        hout[hoff] = hr; hout[hoff + 1] = hi;
      }
    }
    __syncthreads();
  }
}

extern "C" void kernel_launch(void* const* d_in, const int* in_sizes, int n_in,
                              void* d_out, int out_size, void* d_ws, size_t ws_size,
                              hipStream_t stream) {
  const float* obs    = (const float*)d_in[0];
  const int*   dones  = (const int*)d_in[1];
  const float* hidden = (const float*)d_in[2];
  const float* dw     = (const float*)d_in[3];
  const float* db     = (const float*)d_in[4];
  const float* Lre    = (const float*)d_in[5];
  const float* Lim    = (const float*)d_in[6];
  const float* Bp     = (const float*)d_in[7];
  const float* Cp     = (const float*)d_in[8];
  const float* Dv     = (const float*)d_in[9];
  const float* lstep  = (const float*)d_in[10];
  const float* nsc    = (const float*)d_in[11];
  const float* nbi    = (const float*)d_in[12];
  const float* gw     = (const float*)d_in[13];
  const float* gb     = (const float*)d_in[14];

  float* hout = (float*)d_out;
  float* x = hout + (size_t)2 * NB * NP * 2;   // 65536 floats offset

  unsigned char* wsb = (unsigned char*)d_ws;
  unsigned short* wTb = (unsigned short*)(wsb + WTB_OFF);
  int* flagv = (int*)(wsb + FLAG_OFF);

  k_setup<<<dim3(64, 2), 256, 0, stream>>>(Lre, Lim, Bp, Cp, lstep, gw, dw, wsb);
  k_dense<<<NM / 128, 256, 0, stream>>>(obs, wTb, db, x);
  k_layer<<<dim3(NB, 2), 512, 0, stream>>>(x, dones, wsb + CONST_OFF, hidden, hout,
                                           nsc, nbi, Dv, gb, flagv);
}

// Round 10
// 329.086 us; speedup vs baseline: 1.0100x; 1.0100x over previous
//
#include <hip/hip_runtime.h>

#define NB 128
#define NT 1024
#define NOBS 512
#define NH 64
#define NP 128
#define NM (NB*NT)      // 131072 rows
#define NN2 256
#define NCH 16
#define CHL 64

typedef short bf16x8 __attribute__((ext_vector_type(8)));
typedef float f32x4 __attribute__((ext_vector_type(4)));

// ---- ws layout (bytes) ----
#define CONST_OFF ((size_t)91226112)
#define CONST_STRIDE ((size_t)131072)
#define WTB_OFF   ((size_t)92274688)
// const block: [0,1024) lambar f32x2; [1024,33792) Bglob bf16 [256][64];
// [33792,66560) Cglob bf16 [64][256]; [66560,74752) gwT bf16 [64][64]

__device__ __forceinline__ unsigned short f2b(float f) {
  unsigned int u = __float_as_uint(f);
  u = u + 0x7fffu + ((u >> 16) & 1u);
  return (unsigned short)(u >> 16);
}
__device__ __forceinline__ float b2f(unsigned short s) {
  return __uint_as_float(((unsigned int)s) << 16);
}
__device__ __forceinline__ unsigned int pk2(float lo, float hi) {
  return (unsigned int)f2b(lo) | ((unsigned int)f2b(hi) << 16);
}

// ---------------- setup: per-layer constant tables + dense W^T bf16 ----------------
__global__ __launch_bounds__(256) void k_setup(const float* Lre, const float* Lim,
    const float* Bp, const float* Cp, const float* lstep, const float* gw,
    const float* dw, unsigned char* wsb) {
  int l = blockIdx.y;
  int idx = blockIdx.x * 256 + threadIdx.x;   // [0,16384)
  unsigned char* cb = wsb + CONST_OFF + (size_t)l * CONST_STRIDE;
  float2* lambar = (float2*)cb;
  unsigned short* Bglob = (unsigned short*)(cb + 1024);
  unsigned short* Cglob = (unsigned short*)(cb + 33792);
  unsigned short* gwT   = (unsigned short*)(cb + 66560);
  {
    int n = idx >> 6, h = idx & 63, p = n >> 1, c = n & 1;
    float step = expf(lstep[l * NP + p]);
    float re = Lre[l * NP + p], im = Lim[l * NP + p];
    float er = expf(re * step), ang = im * step;
    float lbr = er * cosf(ang), lbi = er * sinf(ang);
    if (h == 0 && c == 0) lambar[p] = make_float2(lbr, lbi);
    float den = re * re + im * im;
    float nr = lbr - 1.f, ni = lbi;
    float dr = (nr * re + ni * im) / den;
    float di = (ni * re - nr * im) / den;
    size_t bb = ((size_t)(l * NP + p) * NH + h) * 2;
    float b0 = Bp[bb + 0], b1 = Bp[bb + 1];
    float vr = dr * b0 - di * b1;
    float vi = dr * b1 + di * b0;
    Bglob[n * 64 + h] = f2b(c ? vi : vr);
  }
  {
    int h = idx >> 8, n = idx & 255, p = n >> 1;
    size_t base = ((size_t)(l * NH + h) * NP + p) * 2;
    float val = (n & 1) ? (-2.f * Cp[base + 1]) : (2.f * Cp[base + 0]);
    Cglob[h * 256 + n] = f2b(val);
  }
  if (idx < 4096) {
    int n = idx >> 6, k = idx & 63;
    gwT[n * 64 + k] = f2b(gw[(size_t)(l * NH + k) * NH + n]);
  }
  {
    int idx2 = l * 16384 + idx;
    int h = idx2 >> 9, k = idx2 & 511;
    ((unsigned short*)(wsb + WTB_OFF))[h * 512 + k] = f2b(dw[(size_t)k * NH + h]);
  }
}

// ---------------- dense: x = obs @ W + b (pipelined, BK=64) ----------------
__global__ __launch_bounds__(256) void k_dense(const float* __restrict__ obs,
    const unsigned short* __restrict__ wTb, const float* __restrict__ bias,
    float* __restrict__ xout) {
  __shared__ __align__(16) unsigned short As[128][72];
  __shared__ __align__(16) unsigned short Bs[64][72];
  int tid = threadIdx.x, lane = tid & 63, wv = tid >> 6;
  int row0 = blockIdx.x * 128;
  f32x4 acc[2][4] = {};
  float bcol[4];
#pragma unroll
  for (int ct = 0; ct < 4; ++ct) bcol[ct] = bias[ct * 16 + (lane & 15)];
  float4 ra[8];
  uint4 rb[2];
#pragma unroll
  for (int i = 0; i < 8; ++i) {
    int id = tid + i * 256;
    ra[i] = *(const float4*)(obs + (size_t)(row0 + (id >> 4)) * NOBS + (id & 15) * 4);
  }
#pragma unroll
  for (int i = 0; i < 2; ++i) {
    int id = tid + i * 256;
    rb[i] = *(const uint4*)(wTb + (id >> 3) * 512 + (id & 7) * 8);
  }
  for (int kt = 0; kt < 8; ++kt) {
#pragma unroll
    for (int i = 0; i < 8; ++i) {
      int id = tid + i * 256;
      ushort4 o; o.x = f2b(ra[i].x); o.y = f2b(ra[i].y); o.z = f2b(ra[i].z); o.w = f2b(ra[i].w);
      *(ushort4*)&As[id >> 4][(id & 15) * 4] = o;
    }
#pragma unroll
    for (int i = 0; i < 2; ++i) {
      int id = tid + i * 256;
      *(uint4*)&Bs[id >> 3][(id & 7) * 8] = rb[i];
    }
    __syncthreads();
    if (kt < 7) {
      int k0 = (kt + 1) * 64;
#pragma unroll
      for (int i = 0; i < 8; ++i) {
        int id = tid + i * 256;
        ra[i] = *(const float4*)(obs + (size_t)(row0 + (id >> 4)) * NOBS + k0 + (id & 15) * 4);
      }
#pragma unroll
      for (int i = 0; i < 2; ++i) {
        int id = tid + i * 256;
        rb[i] = *(const uint4*)(wTb + (id >> 3) * 512 + k0 + (id & 7) * 8);
      }
    }
#pragma unroll
    for (int kc = 0; kc < 2; ++kc) {
      bf16x8 a0 = *(const bf16x8*)&As[wv * 32 + (lane & 15)][kc * 32 + (lane >> 4) * 8];
      bf16x8 a1 = *(const bf16x8*)&As[wv * 32 + 16 + (lane & 15)][kc * 32 + (lane >> 4) * 8];
#pragma unroll
      for (int ct = 0; ct < 4; ++ct) {
        bf16x8 bb = *(const bf16x8*)&Bs[ct * 16 + (lane & 15)][kc * 32 + (lane >> 4) * 8];
        acc[0][ct] = __builtin_amdgcn_mfma_f32_16x16x32_bf16(a0, bb, acc[0][ct], 0, 0, 0);
        acc[1][ct] = __builtin_amdgcn_mfma_f32_16x16x32_bf16(a1, bb, acc[1][ct], 0, 0, 0);
      }
    }
    __syncthreads();
  }
  float* Os = (float*)&As[0][0];   // [64][68]
#pragma unroll
  for (int pass = 0; pass < 2; ++pass) {
    if ((wv >> 1) == pass) {
#pragma unroll
      for (int rt = 0; rt < 2; ++rt)
#pragma unroll
        for (int ct = 0; ct < 4; ++ct)
#pragma unroll
          for (int e = 0; e < 4; ++e) {
            int rl = (wv & 1) * 32 + rt * 16 + (lane >> 4) * 4 + e;
            int col = ct * 16 + (lane & 15);
            Os[rl * 68 + col] = acc[rt][ct][e] + bcol[ct];
          }
    }
    __syncthreads();
    {
      int r = tid >> 2, seg = tid & 3;
#pragma unroll
      for (int i = 0; i < 4; ++i)
        *(float4*)(xout + (size_t)(row0 + pass * 64 + r) * NH + seg * 16 + i * 4) =
            *(const float4*)&Os[r * 68 + seg * 16 + i * 4];
    }
    __syncthreads();
  }
}

// ---------------- mega-fused BOTH-layers kernel: R6-proven 3-barrier skeleton ----------------
// P1a: w0-3 LN(i)->xnS,murs | w4-7 ysMFMA+GELU(i-2)->Ys
// P1b: w4-7 GLU(i-2) (reads Ys across barrier) + residual + x store
// P2 : w0-3 BuMFMA(i)->BuS[i&1] | threads 256-383 register-scan(i-1) on BuS[(i-1)&1]
__global__ __launch_bounds__(512, 1) void k_2layers(float* __restrict__ x,
    const int* __restrict__ dones, const unsigned char* __restrict__ cb0,
    const float* __restrict__ hidden, float* __restrict__ hout,
    const float* __restrict__ nsc0, const float* __restrict__ nbi0,
    const float* __restrict__ Dv0, const float* __restrict__ gb0) {
  __shared__ __align__(16) unsigned short Bs[256][72];      // 36864
  __shared__ __align__(16) unsigned short Cs[64][264];      // 33792
  __shared__ __align__(16) unsigned short BuS[2][64][264];  // 67584
  __shared__ __align__(16) unsigned short xnS[64][72];      // 9216
  __shared__ __align__(16) unsigned short Ys[64][72];       // 9216
  __shared__ float murs[4][64][2];                          // 2048
  __shared__ unsigned int dmask[32];                        // 128  => 158848 B
  int tid = threadIdx.x, lane = tid & 63, wv = tid >> 6;
  int b = blockIdx.x;

  // dones -> bitmask (verified via h_out in R8)
  {
    unsigned long long m0 = __ballot(dones[b * NT + tid] != 0);
    unsigned long long m1 = __ballot(dones[b * NT + 512 + tid] != 0);
    if (lane == 0) {
      dmask[wv * 2]          = (unsigned int)m0;
      dmask[wv * 2 + 1]      = (unsigned int)(m0 >> 32);
      dmask[16 + wv * 2]     = (unsigned int)m1;
      dmask[16 + wv * 2 + 1] = (unsigned int)(m1 >> 32);
    }
  }

#pragma unroll 1
  for (int l = 0; l < 2; ++l) {
    const unsigned char* cb = cb0 + (size_t)l * CONST_STRIDE;
    const float* nsc = nsc0 + l * NH;
    const float* nbi = nbi0 + l * NH;
    const float* Dv  = Dv0 + l * NH;
    const float* gb  = gb0 + l * NH;
    const unsigned short* Bglob = (const unsigned short*)(cb + 1024);
    const unsigned short* Cglob = (const unsigned short*)(cb + 33792);
    const unsigned short* gwT = (const unsigned short*)(cb + 66560);

    // stage tables for this layer (prior phase ended with __syncthreads)
    {
      int r = tid >> 1, h0 = (tid & 1) * 32;
#pragma unroll
      for (int i = 0; i < 4; ++i)
        *(uint4*)&Bs[r][h0 + i * 8] = *(const uint4*)(Bglob + r * 64 + h0 + i * 8);
    }
    {
      int r = tid >> 3, s0 = (tid & 7) * 32;
#pragma unroll
      for (int i = 0; i < 4; ++i)
        *(uint4*)&Cs[r][s0 + i * 8] = *(const uint4*)(Cglob + r * 256 + s0 + i * 8);
    }

    // role preloads
    float4 pre0, pre1, pre2, pre3;
    float nscr[16], nbir[16];
    float lamr = 0.f, lami = 0.f, hr = 0.f, hi = 0.f;
    float Dr[4], nscc[4], nbic[4], gbr[4];
    bf16x8 gfr[2][4];
    if (tid < 256) {
      int q = tid & 3;
#pragma unroll
      for (int j = 0; j < 16; ++j) { nscr[j] = nsc[q * 16 + j]; nbir[j] = nbi[q * 16 + j]; }
      int r = tid >> 2;
      const float* xr = x + ((size_t)b * NT + r) * NH + q * 16;
      pre0 = *(const float4*)(xr);     pre1 = *(const float4*)(xr + 4);
      pre2 = *(const float4*)(xr + 8); pre3 = *(const float4*)(xr + 12);
    } else {
#pragma unroll
      for (int ct = 0; ct < 4; ++ct) {
        int col = ct * 16 + (lane & 15);
        Dr[ct] = Dv[col]; nscc[ct] = nsc[col]; nbic[ct] = nbi[col]; gbr[ct] = gb[col];
      }
#pragma unroll
      for (int kc = 0; kc < 2; ++kc)
#pragma unroll
        for (int ct = 0; ct < 4; ++ct)
          gfr[kc][ct] = *(const bf16x8*)(gwT + (ct * 16 + (lane & 15)) * 64 + kc * 32 + (lane >> 4) * 8);
      if (tid < 384) {
        int p = tid - 256;
        float2 lm = ((const float2*)cb)[p];
        lamr = lm.x; lami = lm.y;
        size_t hoff = (((size_t)l * NB + b) * NP + p) * 2;
        hr = hidden[hoff]; hi = hidden[hoff + 1];
      }
    }
    __syncthreads();

#pragma unroll 1
    for (int i = 0; i < NCH + 2; ++i) {
      float yreg[4][4], xres[4][4];
      // ---------------- P1a ----------------
      if (tid < 256) {
        if (i < NCH) {
          float vv[16];
          *(float4*)&vv[0] = pre0;  *(float4*)&vv[4] = pre1;
          *(float4*)&vv[8] = pre2;  *(float4*)&vv[12] = pre3;
          int r = tid >> 2, q = tid & 3;
          if (i < NCH - 1) {
            const float* xr = x + ((size_t)b * NT + (i + 1) * CHL + r) * NH + q * 16;
            pre0 = *(const float4*)(xr);     pre1 = *(const float4*)(xr + 4);
            pre2 = *(const float4*)(xr + 8); pre3 = *(const float4*)(xr + 12);
          }
          float s = 0.f, s2 = 0.f;
#pragma unroll
          for (int j = 0; j < 16; ++j) { s += vv[j]; s2 += vv[j] * vv[j]; }
          s += __shfl_xor(s, 1); s2 += __shfl_xor(s2, 1);
          s += __shfl_xor(s, 2); s2 += __shfl_xor(s2, 2);
          float mu = s * 0.015625f;
          float var = s2 * 0.015625f - mu * mu;
          float rs = rsqrtf(var + 1e-6f);
          if (q == 0) { murs[i & 3][r][0] = mu; murs[i & 3][r][1] = rs; }
#pragma unroll
          for (int k = 0; k < 8; ++k) {
            float a0 = (vv[2 * k] - mu) * rs * nscr[2 * k] + nbir[2 * k];
            float a1 = (vv[2 * k + 1] - mu) * rs * nscr[2 * k + 1] + nbir[2 * k + 1];
            *(unsigned int*)&xnS[r][q * 16 + 2 * k] = pk2(a0, a1);
          }
        }
      } else if (i >= 2) {
        int j = i - 2, wv2 = wv - 4;
#pragma unroll
        for (int ct = 0; ct < 4; ++ct)
#pragma unroll
          for (int e = 0; e < 4; ++e) {
            int rl = wv2 * 16 + (lane >> 4) * 4 + e;
            xres[ct][e] = x[((size_t)b * NT + j * CHL + rl) * NH + ct * 16 + (lane & 15)];
          }
        f32x4 acc[4] = {};
        const unsigned short (*Bu)[264] = BuS[j & 1];
#pragma unroll
        for (int kc = 0; kc < 8; ++kc) {
          bf16x8 a = *(const bf16x8*)&Bu[wv2 * 16 + (lane & 15)][kc * 32 + (lane >> 4) * 8];
#pragma unroll
          for (int ct = 0; ct < 4; ++ct) {
            bf16x8 bbf = *(const bf16x8*)&Cs[ct * 16 + (lane & 15)][kc * 32 + (lane >> 4) * 8];
            acc[ct] = __builtin_amdgcn_mfma_f32_16x16x32_bf16(a, bbf, acc[ct], 0, 0, 0);
          }
        }
#pragma unroll
        for (int ct = 0; ct < 4; ++ct)
#pragma unroll
          for (int e = 0; e < 4; ++e) {
            int rl = wv2 * 16 + (lane >> 4) * 4 + e;
            float mu = murs[j & 3][rl][0], rs = murs[j & 3][rl][1];
            float xnv = (xres[ct][e] - mu) * rs * nscc[ct] + nbic[ct];
            float yv = acc[ct][e] + Dr[ct] * xnv;
            float t3 = 0.7978845608f * (yv + 0.044715f * yv * yv * yv);
            float u = __expf(2.f * t3);
            yv = 0.5f * yv * (2.f - 2.f / (u + 1.f));
            yreg[ct][e] = yv;
            Ys[rl][ct * 16 + (lane & 15)] = f2b(yv);
          }
      }
      __syncthreads();
      // ---------------- P1b ----------------
      if (tid >= 256 && i >= 2) {
        int j = i - 2, wv2 = wv - 4;
        f32x4 gacc[4] = {};
#pragma unroll
        for (int kc = 0; kc < 2; ++kc) {
          bf16x8 a = *(const bf16x8*)&Ys[wv2 * 16 + (lane & 15)][kc * 32 + (lane >> 4) * 8];
#pragma unroll
          for (int ct = 0; ct < 4; ++ct)
            gacc[ct] = __builtin_amdgcn_mfma_f32_16x16x32_bf16(a, gfr[kc][ct], gacc[ct], 0, 0, 0);
        }
#pragma unroll
        for (int ct = 0; ct < 4; ++ct)
#pragma unroll
          for (int e = 0; e < 4; ++e) {
            int rl = wv2 * 16 + (lane >> 4) * 4 + e;
            float g = gacc[ct][e] + gbr[ct];
            float sg = 1.f / (1.f + __expf(-g));
            x[((size_t)b * NT + j * CHL + rl) * NH + ct * 16 + (lane & 15)] =
                xres[ct][e] + yreg[ct][e] * sg;
          }
      }
      __syncthreads();
      // ---------------- P2 ----------------
      if (tid < 256) {
        if (i < NCH) {
          // BuMFMA(i), swapped operands -> Bu^T tile, packed u32 writes (R7-proven)
          f32x4 acc[16] = {};
#pragma unroll
          for (int kc = 0; kc < 2; ++kc) {
            bf16x8 a = *(const bf16x8*)&xnS[wv * 16 + (lane & 15)][kc * 32 + (lane >> 4) * 8];
#pragma unroll
            for (int ct = 0; ct < 16; ++ct) {
              bf16x8 bbf = *(const bf16x8*)&Bs[ct * 16 + (lane & 15)][kc * 32 + (lane >> 4) * 8];
              acc[ct] = __builtin_amdgcn_mfma_f32_16x16x32_bf16(bbf, a, acc[ct], 0, 0, 0);
            }
          }
          unsigned short (*Bu)[264] = BuS[i & 1];
          int t = wv * 16 + (lane & 15), cb4 = (lane >> 4) * 4;
#pragma unroll
          for (int ct = 0; ct < 16; ++ct) {
            *(unsigned int*)&Bu[t][ct * 16 + cb4]     = pk2(acc[ct][0], acc[ct][1]);
            *(unsigned int*)&Bu[t][ct * 16 + cb4 + 2] = pk2(acc[ct][2], acc[ct][3]);
          }
        }
      } else if (tid < 384 && i >= 1 && i <= NCH) {
        // register-bulk scan(ch=i-1) on BuS[(i-1)&1] (logic verified via h_out in R8)
        int ch = i - 1, p = tid - 256;
        unsigned short (*Bu)[264] = BuS[ch & 1];
        unsigned int m0 = dmask[ch * 2], m1 = dmask[ch * 2 + 1];
        unsigned int v[64];
#pragma unroll
        for (int t = 0; t < 64; ++t) v[t] = *(const unsigned int*)&Bu[t][2 * p];
#pragma unroll
        for (int t = 0; t < 64; ++t) {
          float bur = b2f((unsigned short)(v[t] & 0xffffu));
          float bui = b2f((unsigned short)(v[t] >> 16));
          bool d = (((t < 32 ? m0 : m1) >> (t & 31)) & 1u) != 0;
          float nr = lamr * hr - lami * hi + bur;
          float ni = lamr * hi + lami * hr + bui;
          hr = d ? bur : nr;
          hi = d ? bui : ni;
          v[t] = pk2(hr, hi);
        }
#pragma unroll
        for (int t = 0; t < 64; ++t) *(unsigned int*)&Bu[t][2 * p] = v[t];
        if (ch == NCH - 1) {
          size_t hoff = (((size_t)l * NB + b) * NP + p) * 2;
          hout[hoff] = hr; hout[hoff + 1] = hi;
        }
      }
      __syncthreads();
    }
  }
}

extern "C" void kernel_launch(void* const* d_in, const int* in_sizes, int n_in,
                              void* d_out, int out_size, void* d_ws, size_t ws_size,
                              hipStream_t stream) {
  const float* obs    = (const float*)d_in[0];
  const int*   dones  = (const int*)d_in[1];
  const float* hidden = (const float*)d_in[2];
  const float* dw     = (const float*)d_in[3];
  const float* db     = (const float*)d_in[4];
  const float* Lre    = (const float*)d_in[5];
  const float* Lim    = (const float*)d_in[6];
  const float* Bp     = (const float*)d_in[7];
  const float* Cp     = (const float*)d_in[8];
  const float* Dv     = (const float*)d_in[9];
  const float* lstep  = (const float*)d_in[10];
  const float* nsc    = (const float*)d_in[11];
  const float* nbi    = (const float*)d_in[12];
  const float* gw     = (const float*)d_in[13];
  const float* gb     = (const float*)d_in[14];

  float* hout = (float*)d_out;
  float* x = hout + (size_t)2 * NB * NP * 2;   // 65536 floats offset

  unsigned char* wsb = (unsigned char*)d_ws;
  unsigned short* wTb = (unsigned short*)(wsb + WTB_OFF);

  k_setup<<<dim3(64, 2), 256, 0, stream>>>(Lre, Lim, Bp, Cp, lstep, gw, dw, wsb);
  k_dense<<<NM / 128, 256, 0, stream>>>(obs, wTb, db, x);
  k_2layers<<<NB, 512, 0, stream>>>(x, dones, wsb + CONST_OFF, hidden, hout,
                                    nsc, nbi, Dv, gb);
}